// Round 6
// baseline (501.898 us; speedup 1.0000x reference)
//
#include <hip/hip_runtime.h>
#include <hip/hip_bf16.h>
#include <cstddef>

// ---------------------------------------------------------------------------
// GNN layer (RED-GNN style), MI355X — round 6.
// vs round 5 (350 us): edge gathers were random (FETCH 248 MB = 5x table
// size). Now edges are processed in SUB-SORTED order (hidden/hsWs gathers
// become sequential runs) and aggregated in OBJ-SORTED order with linearly
// read packed metadata (no eidx->edges double indirection).
//   pipeline: memset | hsWs=hidden@Ws | Br,Cq | hist(+out_obj) |
//             scan(sub) scan(obj) | scatter(build both CSRs) |
//             edge_sorted(message NT, alpha) | agg(recompute+@W_h)
// Packing: meta_sub = int2{sub, (rel<<8)|r_idx}; meta_obj = (rel<<17)|sub
//          (sub<2^17, rel<512, r_idx<256).
// ---------------------------------------------------------------------------

typedef float f32x4 __attribute__((ext_vector_type(4)));

static __device__ __forceinline__ void nt_store4(float* p, float4 v) {
    f32x4 t = {v.x, v.y, v.z, v.w};
    __builtin_nontemporal_store(t, (f32x4*)p);
}
#define NT_STORE(p, v) __builtin_nontemporal_store((v), (p))

// Y[row] = X[row] @ W. W staged in LDS. block=256 = 4 rows x 64 cols.
__global__ void matmul64_kernel(const float* __restrict__ X,
                                const float* __restrict__ W,
                                float* __restrict__ Y, int nrows) {
    __shared__ float Wl[64][64];
    int tid = threadIdx.x;
    for (int i = tid; i < 4096; i += 256) Wl[i >> 6][i & 63] = W[i];
    __syncthreads();
    int col = tid & 63;
    int r4  = tid >> 6;
    for (long row = (long)blockIdx.x * 4 + r4; row < nrows;
         row += (long)gridDim.x * 4) {
        float xv  = X[row * 64 + col];
        float acc = 0.0f;
#pragma unroll
        for (int k = 0; k < 64; ++k)
            acc = fmaf(__shfl(xv, k, 64), Wl[k][col], acc);
        Y[row * 64 + col] = acc;
    }
}

// B_r = rela@Wr ; C_q = rela[q_rel]@Wqr + Wqr_b.
__global__ void rel_precompute_kernel(const float* __restrict__ rela,
                                      const float* __restrict__ Wr,
                                      const float* __restrict__ Wqr,
                                      const float* __restrict__ Wqr_b,
                                      const int* __restrict__ q_rel,
                                      float* __restrict__ Br,
                                      float* __restrict__ Cq,
                                      int nrel, int nq) {
    __shared__ float W1[64][64];
    __shared__ float W2[64][64];
    int tid = threadIdx.x;
    for (int i = tid; i < 4096; i += 256) {
        W1[i >> 6][i & 63] = Wr[i];
        W2[i >> 6][i & 63] = Wqr[i];
    }
    __syncthreads();
    int col = tid & 63;
    int r4  = tid >> 6;
    int total = nrel + nq;
    for (int row = blockIdx.x * 4 + r4; row < total; row += gridDim.x * 4) {
        if (row < nrel) {
            float xv  = rela[(size_t)row * 64 + col];
            float acc = 0.0f;
#pragma unroll
            for (int k = 0; k < 64; ++k)
                acc = fmaf(__shfl(xv, k, 64), W1[k][col], acc);
            Br[(size_t)row * 64 + col] = acc;
        } else {
            int q  = row - nrel;
            int rr = q_rel[q];
            float xv  = rela[(size_t)rr * 64 + col];
            float acc = Wqr_b[col];
#pragma unroll
            for (int k = 0; k < 64; ++k)
                acc = fmaf(__shfl(xv, k, 64), W2[k][col], acc);
            Cq[(size_t)q * 64 + col] = acc;
        }
    }
}

// Histograms for both CSRs + the out_obj output (linear NT write).
__global__ void hist_kernel(const int* __restrict__ edges,
                            int* __restrict__ cnt_sub,
                            int* __restrict__ cnt_obj,
                            float* __restrict__ out_obj, int nedge) {
    int e = blockIdx.x * 256 + threadIdx.x;
    if (e >= nedge) return;
    int sub = edges[(size_t)e * 6 + 4];
    int obj = edges[(size_t)e * 6 + 5];
    atomicAdd(&cnt_sub[sub], 1);
    atomicAdd(&cnt_obj[obj], 1);
    NT_STORE(&out_obj[e], (float)obj);
}

// ---- 3-pass exclusive scan over cnt[n], chunk = 1024 ----

__global__ void scan_reduce_kernel(const int* __restrict__ cnt,
                                   int* __restrict__ bsum, int n) {
    int i = blockIdx.x * 1024 + threadIdx.x;
    int v = (i < n) ? cnt[i] : 0;
    int lane = threadIdx.x & 63, w = threadIdx.x >> 6;
#pragma unroll
    for (int m = 1; m < 64; m <<= 1) v += __shfl_xor(v, m, 64);
    __shared__ int ws[16];
    if (lane == 0) ws[w] = v;
    __syncthreads();
    if (threadIdx.x == 0) {
        int s = 0;
#pragma unroll
        for (int k = 0; k < 16; ++k) s += ws[k];
        bsum[blockIdx.x] = s;
    }
}

__global__ void scan_top_kernel(int* __restrict__ bsum, int nb) {
    int tid = threadIdx.x;
    int lane = tid & 63, w = tid >> 6;
    int v = (tid < nb) ? bsum[tid] : 0;
    int ins = v;
#pragma unroll
    for (int off = 1; off < 64; off <<= 1) {
        int t = __shfl_up(ins, off, 64);
        if (lane >= off) ins += t;
    }
    __shared__ int ws[16];
    __shared__ int wo[16];
    if (lane == 63) ws[w] = ins;
    __syncthreads();
    if (tid == 0) {
        int s = 0;
        for (int k = 0; k < 16; ++k) { wo[k] = s; s += ws[k]; }
    }
    __syncthreads();
    if (tid < nb) bsum[tid] = wo[w] + ins - v;   // exclusive
}

// out1 (and optionally out2) = exclusive scan result.
__global__ void scan_apply_kernel(const int* __restrict__ cnt,
                                  const int* __restrict__ boffs,
                                  int* __restrict__ out1,
                                  int* __restrict__ out2, int n) {
    int i = blockIdx.x * 1024 + threadIdx.x;
    int lane = threadIdx.x & 63, w = threadIdx.x >> 6;
    int v = (i < n) ? cnt[i] : 0;
    int ins = v;
#pragma unroll
    for (int off = 1; off < 64; off <<= 1) {
        int t = __shfl_up(ins, off, 64);
        if (lane >= off) ins += t;
    }
    __shared__ int ws[16];
    __shared__ int wo[16];
    if (lane == 63) ws[w] = ins;
    __syncthreads();
    if (threadIdx.x == 0) {
        int s = 0;
        for (int k = 0; k < 16; ++k) { wo[k] = s; s += ws[k]; }
    }
    __syncthreads();
    if (i < n) {
        int r = boffs[blockIdx.x] + wo[w] + ins - v;
        out1[i] = r;
        if (out2) out2[i] = r;
    }
}

// Build BOTH sorted orders (counting sort via atomic cursors).
__global__ void scatter_kernel(const int* __restrict__ edges,
                               int* __restrict__ cur_sub,
                               int* __restrict__ cur_obj,
                               int2* __restrict__ meta_sub,
                               int* __restrict__ eid_sub,
                               int* __restrict__ meta_obj,
                               int* __restrict__ eid_obj, int nedge) {
    int e = blockIdx.x * 256 + threadIdx.x;
    if (e >= nedge) return;
    int r_idx = edges[(size_t)e * 6 + 0];
    int rel   = edges[(size_t)e * 6 + 2];
    int sub   = edges[(size_t)e * 6 + 4];
    int obj   = edges[(size_t)e * 6 + 5];
    int p1 = atomicAdd(&cur_sub[sub], 1);
    meta_sub[p1] = make_int2(sub, (rel << 8) | r_idx);
    eid_sub[p1]  = e;
    int p2 = atomicAdd(&cur_obj[obj], 1);
    meta_obj[p2] = (rel << 17) | sub;
    eid_obj[p2]  = e;
}

// Edge pass in SUB-SORTED order: 4 edges/wave, 16 lanes x float4.
__global__ void edge_kernel(const int2* __restrict__ meta_sub,
                            const int* __restrict__ eid_sub,
                            const float* __restrict__ hidden,
                            const float* __restrict__ rela,
                            const float* __restrict__ hsWs,
                            const float* __restrict__ Br,
                            const float* __restrict__ Cq,
                            const float* __restrict__ w_alpha_w,
                            const float* __restrict__ w_alpha_b,
                            float* __restrict__ out_alpha,
                            float* __restrict__ out_message,
                            float* __restrict__ out_alpha_temp,
                            int nedge) {
    int tid  = threadIdx.x;
    int lane = tid & 63;
    int g    = lane >> 4;        // edge slot in wave (0..3)
    int s    = lane & 15;        // feature chunk (4 floats)
    long p0  = ((long)blockIdx.x * 4 + (tid >> 6)) * 4;
    if (p0 >= nedge) return;
    long p = p0 + g;
    bool valid = (p < nedge);

    // 4 edges' packed metadata (8 ints) + ids (4 ints): linear loads.
    int mi = 0;
    if (lane < 8 && (p0 * 2 + lane) < (long)nedge * 2)
        mi = ((const int*)meta_sub)[p0 * 2 + lane];
    int eld = 0;
    if (lane < 4 && (p0 + lane) < nedge) eld = eid_sub[p0 + lane];
    int A = __shfl(mi, g * 2 + 0, 64);
    int B = __shfl(mi, g * 2 + 1, 64);
    long e = __shfl(eld, g, 64);
    int sub = A, rel = B >> 8, r_idx = B & 255;
    if (!valid) { sub = 0; rel = 0; r_idx = 0; }

    const float4 h4 = *(const float4*)(hsWs + (size_t)sub  * 64 + s * 4);
    const float4 b4 = *(const float4*)(Br   + (size_t)rel  * 64 + s * 4);
    const float4 c4 = *(const float4*)(Cq   + (size_t)r_idx* 64 + s * 4);
    const float4 hv = *(const float4*)(hidden + (size_t)sub * 64 + s * 4);
    const float4 rv = *(const float4*)(rela   + (size_t)rel * 64 + s * 4);
    const float4 wa = *(const float4*)(w_alpha_w + s * 4);

    float4 a4;
    a4.x = fmaxf(h4.x + b4.x + c4.x, 0.0f);
    a4.y = fmaxf(h4.y + b4.y + c4.y, 0.0f);
    a4.z = fmaxf(h4.z + b4.z + c4.z, 0.0f);
    a4.w = fmaxf(h4.w + b4.w + c4.w, 0.0f);

    float part = a4.x * wa.x + a4.y * wa.y + a4.z * wa.z + a4.w * wa.w;
    part += __shfl_xor(part, 1, 64);
    part += __shfl_xor(part, 2, 64);
    part += __shfl_xor(part, 4, 64);
    part += __shfl_xor(part, 8, 64);

    float at    = part + w_alpha_b[0];
    float alpha = 1.0f / (1.0f + __expf(-at));

    float4 m4;
    m4.x = alpha * (hv.x + rv.x);
    m4.y = alpha * (hv.y + rv.y);
    m4.z = alpha * (hv.z + rv.z);
    m4.w = alpha * (hv.w + rv.w);

    if (valid) {
        nt_store4(out_message + e * 64 + s * 4, m4);   // scattered 256B NT
        if (s == 0) {
            out_alpha[e]      = alpha;   // cacheable: re-read by agg
            out_alpha_temp[e] = at;      // 4 MB region, L2 merges lines
        }
    }
}

// Aggregation in OBJ-SORTED order: linear packed metadata, recompute msg,
// then hidden_new = agg @ W_h. One node per wave.
__global__ void agg_matmul_kernel(const float* __restrict__ out_alpha,
                                  const int* __restrict__ meta_obj,
                                  const int* __restrict__ eid_obj,
                                  const float* __restrict__ hidden,
                                  const float* __restrict__ rela,
                                  const int* __restrict__ offs,
                                  const int* __restrict__ cnt,
                                  const float* __restrict__ Wh,
                                  float* __restrict__ hidden_new,
                                  int nnode) {
    __shared__ float Wl[64][64];
    int tid = threadIdx.x;
    for (int i = tid; i < 4096; i += 256) Wl[i >> 6][i & 63] = Wh[i];
    __syncthreads();
    int lane = tid & 63;
    int g    = lane >> 4;
    int s    = lane & 15;
    int wv   = tid >> 6;
    for (long node = (long)blockIdx.x * 4 + wv; node < nnode;
         node += (long)gridDim.x * 4) {
        int beg = offs[node];
        int num = cnt[node];
        float4 acc = make_float4(0.f, 0.f, 0.f, 0.f);
        for (int base = 0; base < num; base += 64) {
            int chunk = min(64, num - base);
            // phase 1: metadata for up to 64 edges, LINEAR reads
            int mo = 0;
            float al = 0.0f;             // lanes >= chunk contribute 0
            if (lane < chunk) {
                int pp = beg + base + lane;
                mo = meta_obj[pp];
                al = out_alpha[eid_obj[pp]];
            }
            // phase 2: 4 edges per iteration
            for (int j0 = 0; j0 < chunk; j0 += 4) {
                int j = j0 + g;          // <= 63 always
                int   mok = __shfl(mo, j, 64);
                float alk = __shfl(al, j, 64);
                int sbk = mok & 0x1FFFF;
                int rlk = mok >> 17;
                const float4 hv = *(const float4*)(hidden + (size_t)sbk * 64 + s * 4);
                const float4 rv = *(const float4*)(rela   + (size_t)rlk * 64 + s * 4);
                acc.x = fmaf(alk, hv.x + rv.x, acc.x);
                acc.y = fmaf(alk, hv.y + rv.y, acc.y);
                acc.z = fmaf(alk, hv.z + rv.z, acc.z);
                acc.w = fmaf(alk, hv.w + rv.w, acc.w);
            }
        }
        acc.x += __shfl_xor(acc.x, 16, 64); acc.x += __shfl_xor(acc.x, 32, 64);
        acc.y += __shfl_xor(acc.y, 16, 64); acc.y += __shfl_xor(acc.y, 32, 64);
        acc.z += __shfl_xor(acc.z, 16, 64); acc.z += __shfl_xor(acc.z, 32, 64);
        acc.w += __shfl_xor(acc.w, 16, 64); acc.w += __shfl_xor(acc.w, 32, 64);
        float outv = 0.0f;
#pragma unroll
        for (int k = 0; k < 64; ++k) {
            float xk;
            if      ((k & 3) == 0) xk = __shfl(acc.x, k >> 2, 64);
            else if ((k & 3) == 1) xk = __shfl(acc.y, k >> 2, 64);
            else if ((k & 3) == 2) xk = __shfl(acc.z, k >> 2, 64);
            else                   xk = __shfl(acc.w, k >> 2, 64);
            outv = fmaf(xk, Wl[k][lane], outv);
        }
        NT_STORE(&hidden_new[node * 64 + lane], outv);
    }
}

extern "C" void kernel_launch(void* const* d_in, const int* in_sizes, int n_in,
                              void* d_out, int out_size, void* d_ws, size_t ws_size,
                              hipStream_t stream) {
    const int*   q_rel     = (const int*)d_in[1];
    const float* hidden    = (const float*)d_in[2];
    const int*   edges     = (const int*)d_in[3];
    const float* rela      = (const float*)d_in[5];
    const float* Ws        = (const float*)d_in[6];
    const float* Wr        = (const float*)d_in[7];
    const float* Wqr       = (const float*)d_in[8];
    const float* Wqr_b     = (const float*)d_in[9];
    const float* w_alpha_w = (const float*)d_in[10];
    const float* w_alpha_b = (const float*)d_in[11];
    const float* W_h       = (const float*)d_in[12];

    const int n_node = in_sizes[2] / 64;    // 100000
    const int n_edge = in_sizes[3] / 6;     // 1000000
    const int n_rel  = in_sizes[5] / 64;    // 401
    const int n_q    = in_sizes[1];         // 256

    // Output layout (all fp32, return order).
    float* out            = (float*)d_out;
    float* out_hidden_new = out;
    float* out_alpha      = out + (size_t)n_node * 64;
    float* out_message    = out_alpha + n_edge;
    float* out_obj        = out_message + (size_t)n_edge * 64;
    float* out_alpha_temp = out_obj + n_edge;

    // Workspace layout (~48 MB).
    float* hsWs    = (float*)d_ws;                       // n_node*64
    float* Br      = hsWs + (size_t)n_node * 64;         // n_rel*64
    float* Cq      = Br + (size_t)n_rel * 64;            // n_q*64
    int*   cnt_sub = (int*)(Cq + (size_t)n_q * 64);      // n_node  } contiguous
    int*   cnt_obj = cnt_sub + n_node;                   // n_node  } for memset
    int*   cur_sub = cnt_obj + n_node;                   // n_node
    int*   offs_obj= cur_sub + n_node;                   // n_node
    int*   cur_obj = offs_obj + n_node;                  // n_node
    int*   eid_sub = cur_obj + n_node;                   // n_edge
    int*   meta_obj= eid_sub + n_edge;                   // n_edge
    int*   eid_obj = meta_obj + n_edge;                  // n_edge
    int*   bsum1   = eid_obj + n_edge;                   // 1024
    int*   bsum2   = bsum1 + 1024;                       // 1024
    int2*  meta_sub= (int2*)(bsum2 + 1024);              // n_edge int2

    const int nb = (n_node + 1023) / 1024;               // scan blocks (98)

    (void)hipMemsetAsync(cnt_sub, 0, 2 * (size_t)n_node * sizeof(int), stream);

    // 1) hsWs = hidden @ Ws
    matmul64_kernel<<<2048, 256, 0, stream>>>(hidden, Ws, hsWs, n_node);

    // 2) B_r, C_q
    {
        int grid = (n_rel + n_q + 3) / 4;
        rel_precompute_kernel<<<grid, 256, 0, stream>>>(rela, Wr, Wqr, Wqr_b,
                                                        q_rel, Br, Cq, n_rel, n_q);
    }

    // 3) histograms (+ out_obj)
    hist_kernel<<<(n_edge + 255) / 256, 256, 0, stream>>>(edges, cnt_sub,
                                                          cnt_obj, out_obj,
                                                          n_edge);

    // 4) exclusive scans: cnt_sub -> cur_sub ; cnt_obj -> offs_obj (+cur_obj)
    scan_reduce_kernel<<<nb, 1024, 0, stream>>>(cnt_sub, bsum1, n_node);
    scan_top_kernel<<<1, 1024, 0, stream>>>(bsum1, nb);
    scan_apply_kernel<<<nb, 1024, 0, stream>>>(cnt_sub, bsum1, cur_sub,
                                               (int*)nullptr, n_node);
    scan_reduce_kernel<<<nb, 1024, 0, stream>>>(cnt_obj, bsum2, n_node);
    scan_top_kernel<<<1, 1024, 0, stream>>>(bsum2, nb);
    scan_apply_kernel<<<nb, 1024, 0, stream>>>(cnt_obj, bsum2, offs_obj,
                                               cur_obj, n_node);

    // 5) build both sorted orders
    scatter_kernel<<<(n_edge + 255) / 256, 256, 0, stream>>>(edges, cur_sub,
                                                             cur_obj, meta_sub,
                                                             eid_sub, meta_obj,
                                                             eid_obj, n_edge);

    // 6) edge pass, sub-sorted (sequential gathers)
    {
        int grid = (n_edge + 15) / 16;
        edge_kernel<<<grid, 256, 0, stream>>>(meta_sub, eid_sub, hidden, rela,
                                              hsWs, Br, Cq, w_alpha_w, w_alpha_b,
                                              out_alpha, out_message,
                                              out_alpha_temp, n_edge);
    }

    // 7) aggregation + W_h, obj-sorted (linear metadata)
    agg_matmul_kernel<<<4096, 256, 0, stream>>>(out_alpha, meta_obj, eid_obj,
                                                hidden, rela, offs_obj, cnt_obj,
                                                W_h, out_hidden_new, n_node);
}

// Round 7
// 367.403 us; speedup vs baseline: 1.3661x; 1.3661x over previous
//
#include <hip/hip_runtime.h>
#include <hip/hip_bf16.h>
#include <cstddef>

// ---------------------------------------------------------------------------
// GNN layer (RED-GNN style), MI355X — round 7.
// vs round 5 (350 us) / round 6 (502 us, two-sided sort regression):
// Sort by OBJ only, then ONE merged kernel does all per-edge work inside the
// per-node aggregation walk: linear packed meta read, one set of row gathers
// (hsWs/hidden/Br/Cq/rela), attn->alpha->message, NT-scattered message write,
// register accumulation, epilogue matvec @W_h. The second gather pass (old
// agg recompute, ~250 MB of L2 misses) and all fp32 atomics are gone.
//   pipeline: memset(cnt) | hsWs=hidden@Ws | Br,Cq | hist(+out_obj NT) |
//             scan -> offs,cur | scatter(meta int2) | node_kernel
// Packing: meta = int2{ (rel<<17)|sub , (e<<8)|r_idx }
//          (sub<2^17, rel<512, r_idx<256, e<2^20).
// ---------------------------------------------------------------------------

typedef float f32x4 __attribute__((ext_vector_type(4)));

static __device__ __forceinline__ void nt_store4(float* p, float4 v) {
    f32x4 t = {v.x, v.y, v.z, v.w};
    __builtin_nontemporal_store(t, (f32x4*)p);
}
#define NT_STORE(p, v) __builtin_nontemporal_store((v), (p))

// Y[row] = X[row] @ W. W staged in LDS. block=256 = 4 rows x 64 cols.
__global__ void matmul64_kernel(const float* __restrict__ X,
                                const float* __restrict__ W,
                                float* __restrict__ Y, int nrows) {
    __shared__ float Wl[64][64];
    int tid = threadIdx.x;
    for (int i = tid; i < 4096; i += 256) Wl[i >> 6][i & 63] = W[i];
    __syncthreads();
    int col = tid & 63;
    int r4  = tid >> 6;
    for (long row = (long)blockIdx.x * 4 + r4; row < nrows;
         row += (long)gridDim.x * 4) {
        float xv  = X[row * 64 + col];
        float acc = 0.0f;
#pragma unroll
        for (int k = 0; k < 64; ++k)
            acc = fmaf(__shfl(xv, k, 64), Wl[k][col], acc);
        Y[row * 64 + col] = acc;
    }
}

// B_r = rela@Wr ; C_q = rela[q_rel]@Wqr + Wqr_b.
__global__ void rel_precompute_kernel(const float* __restrict__ rela,
                                      const float* __restrict__ Wr,
                                      const float* __restrict__ Wqr,
                                      const float* __restrict__ Wqr_b,
                                      const int* __restrict__ q_rel,
                                      float* __restrict__ Br,
                                      float* __restrict__ Cq,
                                      int nrel, int nq) {
    __shared__ float W1[64][64];
    __shared__ float W2[64][64];
    int tid = threadIdx.x;
    for (int i = tid; i < 4096; i += 256) {
        W1[i >> 6][i & 63] = Wr[i];
        W2[i >> 6][i & 63] = Wqr[i];
    }
    __syncthreads();
    int col = tid & 63;
    int r4  = tid >> 6;
    int total = nrel + nq;
    for (int row = blockIdx.x * 4 + r4; row < total; row += gridDim.x * 4) {
        if (row < nrel) {
            float xv  = rela[(size_t)row * 64 + col];
            float acc = 0.0f;
#pragma unroll
            for (int k = 0; k < 64; ++k)
                acc = fmaf(__shfl(xv, k, 64), W1[k][col], acc);
            Br[(size_t)row * 64 + col] = acc;
        } else {
            int q  = row - nrel;
            int rr = q_rel[q];
            float xv  = rela[(size_t)rr * 64 + col];
            float acc = Wqr_b[col];
#pragma unroll
            for (int k = 0; k < 64; ++k)
                acc = fmaf(__shfl(xv, k, 64), W2[k][col], acc);
            Cq[(size_t)q * 64 + col] = acc;
        }
    }
}

// Histogram by obj + the out_obj output (linear NT write).
__global__ void hist_kernel(const int* __restrict__ edges,
                            int* __restrict__ cnt_obj,
                            float* __restrict__ out_obj, int nedge) {
    int e = blockIdx.x * 256 + threadIdx.x;
    if (e >= nedge) return;
    int obj = edges[(size_t)e * 6 + 5];
    atomicAdd(&cnt_obj[obj], 1);
    NT_STORE(&out_obj[e], (float)obj);
}

// ---- 3-pass exclusive scan over cnt[n], chunk = 1024 ----

__global__ void scan_reduce_kernel(const int* __restrict__ cnt,
                                   int* __restrict__ bsum, int n) {
    int i = blockIdx.x * 1024 + threadIdx.x;
    int v = (i < n) ? cnt[i] : 0;
    int lane = threadIdx.x & 63, w = threadIdx.x >> 6;
#pragma unroll
    for (int m = 1; m < 64; m <<= 1) v += __shfl_xor(v, m, 64);
    __shared__ int ws[16];
    if (lane == 0) ws[w] = v;
    __syncthreads();
    if (threadIdx.x == 0) {
        int s = 0;
#pragma unroll
        for (int k = 0; k < 16; ++k) s += ws[k];
        bsum[blockIdx.x] = s;
    }
}

__global__ void scan_top_kernel(int* __restrict__ bsum, int nb) {
    int tid = threadIdx.x;
    int lane = tid & 63, w = tid >> 6;
    int v = (tid < nb) ? bsum[tid] : 0;
    int ins = v;
#pragma unroll
    for (int off = 1; off < 64; off <<= 1) {
        int t = __shfl_up(ins, off, 64);
        if (lane >= off) ins += t;
    }
    __shared__ int ws[16];
    __shared__ int wo[16];
    if (lane == 63) ws[w] = ins;
    __syncthreads();
    if (tid == 0) {
        int s = 0;
        for (int k = 0; k < 16; ++k) { wo[k] = s; s += ws[k]; }
    }
    __syncthreads();
    if (tid < nb) bsum[tid] = wo[w] + ins - v;   // exclusive
}

__global__ void scan_apply_kernel(const int* __restrict__ cnt,
                                  const int* __restrict__ boffs,
                                  int* __restrict__ out1,
                                  int* __restrict__ out2, int n) {
    int i = blockIdx.x * 1024 + threadIdx.x;
    int lane = threadIdx.x & 63, w = threadIdx.x >> 6;
    int v = (i < n) ? cnt[i] : 0;
    int ins = v;
#pragma unroll
    for (int off = 1; off < 64; off <<= 1) {
        int t = __shfl_up(ins, off, 64);
        if (lane >= off) ins += t;
    }
    __shared__ int ws[16];
    __shared__ int wo[16];
    if (lane == 63) ws[w] = ins;
    __syncthreads();
    if (threadIdx.x == 0) {
        int s = 0;
        for (int k = 0; k < 16; ++k) { wo[k] = s; s += ws[k]; }
    }
    __syncthreads();
    if (i < n) {
        int r = boffs[blockIdx.x] + wo[w] + ins - v;
        out1[i] = r;
        if (out2) out2[i] = r;
    }
}

// Counting-sort scatter: ONE packed int2 write per edge.
__global__ void scatter_kernel(const int* __restrict__ edges,
                               int* __restrict__ cur_obj,
                               int2* __restrict__ meta, int nedge) {
    int e = blockIdx.x * 256 + threadIdx.x;
    if (e >= nedge) return;
    int r_idx = edges[(size_t)e * 6 + 0];
    int rel   = edges[(size_t)e * 6 + 2];
    int sub   = edges[(size_t)e * 6 + 4];
    int obj   = edges[(size_t)e * 6 + 5];
    int p = atomicAdd(&cur_obj[obj], 1);
    meta[p] = make_int2((rel << 17) | sub, (e << 8) | r_idx);
}

// Merged per-node kernel: all per-edge work + aggregation + @W_h epilogue.
// One wave per node; within a wave: 4 edges/iter, 16 lanes x float4 each.
__global__ void node_kernel(const int2* __restrict__ meta,
                            const float* __restrict__ hsWs,
                            const float* __restrict__ hidden,
                            const float* __restrict__ rela,
                            const float* __restrict__ Br,
                            const float* __restrict__ Cq,
                            const float* __restrict__ w_alpha_w,
                            const float* __restrict__ w_alpha_b,
                            const int* __restrict__ offs,
                            const int* __restrict__ cnt,
                            const float* __restrict__ Wh,
                            float* __restrict__ out_alpha,
                            float* __restrict__ out_message,
                            float* __restrict__ out_alpha_temp,
                            float* __restrict__ hidden_new,
                            int nnode, int nedge) {
    __shared__ float Wl[64][64];
    int tid = threadIdx.x;
    for (int i = tid; i < 4096; i += 256) Wl[i >> 6][i & 63] = Wh[i];
    __syncthreads();
    int lane = tid & 63;
    int g    = lane >> 4;        // edge slot in wave (0..3)
    int s    = lane & 15;        // feature chunk (4 floats)
    int wv   = tid >> 6;
    const float4 wa = *(const float4*)(w_alpha_w + s * 4);
    const float  wb = w_alpha_b[0];

    for (long node = (long)blockIdx.x * 4 + wv; node < nnode;
         node += (long)gridDim.x * 4) {
        int beg = offs[node];
        int num = cnt[node];
        int end = beg + num;
        float4 acc = make_float4(0.f, 0.f, 0.f, 0.f);

        for (int p0 = beg; p0 < end; p0 += 4) {
            // 4 positions' packed meta = 8 consecutive ints (linear read).
            int mi = 0;
            long mofs = (long)p0 * 2 + lane;
            if (lane < 8 && mofs < (long)nedge * 2)
                mi = ((const int*)meta)[mofs];
            int A = __shfl(mi, g * 2 + 0, 64);
            int B = __shfl(mi, g * 2 + 1, 64);
            bool valid = (p0 + g < end);
            int sub   = A & 0x1FFFF;
            int rel   = (A >> 17) & 0x1FF;
            int r_idx = B & 255;
            long e    = ((unsigned)B) >> 8;
            if (!valid) { sub = 0; rel = 0; r_idx = 0; }

            const float4 h4 = *(const float4*)(hsWs + (size_t)sub  * 64 + s * 4);
            const float4 b4 = *(const float4*)(Br   + (size_t)rel  * 64 + s * 4);
            const float4 c4 = *(const float4*)(Cq   + (size_t)r_idx* 64 + s * 4);
            const float4 hv = *(const float4*)(hidden + (size_t)sub * 64 + s * 4);
            const float4 rv = *(const float4*)(rela   + (size_t)rel * 64 + s * 4);

            float4 a4;
            a4.x = fmaxf(h4.x + b4.x + c4.x, 0.0f);
            a4.y = fmaxf(h4.y + b4.y + c4.y, 0.0f);
            a4.z = fmaxf(h4.z + b4.z + c4.z, 0.0f);
            a4.w = fmaxf(h4.w + b4.w + c4.w, 0.0f);

            float part = a4.x * wa.x + a4.y * wa.y + a4.z * wa.z + a4.w * wa.w;
            part += __shfl_xor(part, 1, 64);
            part += __shfl_xor(part, 2, 64);
            part += __shfl_xor(part, 4, 64);
            part += __shfl_xor(part, 8, 64);

            float at    = part + wb;
            float alpha = valid ? 1.0f / (1.0f + __expf(-at)) : 0.0f;

            float4 m4;
            m4.x = alpha * (hv.x + rv.x);
            m4.y = alpha * (hv.y + rv.y);
            m4.z = alpha * (hv.z + rv.z);
            m4.w = alpha * (hv.w + rv.w);

            acc.x += m4.x; acc.y += m4.y; acc.z += m4.z; acc.w += m4.w;

            if (valid) {
                nt_store4(out_message + e * 64 + s * 4, m4);
                if (s == 0) {
                    out_alpha[e]      = alpha;   // cacheable: L2 merges lines
                    out_alpha_temp[e] = at;
                }
            }
        }

        // reduce across the 4 groups; all lanes end with the full row sum
        acc.x += __shfl_xor(acc.x, 16, 64); acc.x += __shfl_xor(acc.x, 32, 64);
        acc.y += __shfl_xor(acc.y, 16, 64); acc.y += __shfl_xor(acc.y, 32, 64);
        acc.z += __shfl_xor(acc.z, 16, 64); acc.z += __shfl_xor(acc.z, 32, 64);
        acc.w += __shfl_xor(acc.w, 16, 64); acc.w += __shfl_xor(acc.w, 32, 64);

        // matvec: out[lane] = sum_k x_k * Wl[k][lane]; x_k in lane k>>2, comp k&3
        float outv = 0.0f;
#pragma unroll
        for (int k = 0; k < 64; ++k) {
            float xk;
            if      ((k & 3) == 0) xk = __shfl(acc.x, k >> 2, 64);
            else if ((k & 3) == 1) xk = __shfl(acc.y, k >> 2, 64);
            else if ((k & 3) == 2) xk = __shfl(acc.z, k >> 2, 64);
            else                   xk = __shfl(acc.w, k >> 2, 64);
            outv = fmaf(xk, Wl[k][lane], outv);
        }
        NT_STORE(&hidden_new[node * 64 + lane], outv);
    }
}

extern "C" void kernel_launch(void* const* d_in, const int* in_sizes, int n_in,
                              void* d_out, int out_size, void* d_ws, size_t ws_size,
                              hipStream_t stream) {
    const int*   q_rel     = (const int*)d_in[1];
    const float* hidden    = (const float*)d_in[2];
    const int*   edges     = (const int*)d_in[3];
    const float* rela      = (const float*)d_in[5];
    const float* Ws        = (const float*)d_in[6];
    const float* Wr        = (const float*)d_in[7];
    const float* Wqr       = (const float*)d_in[8];
    const float* Wqr_b     = (const float*)d_in[9];
    const float* w_alpha_w = (const float*)d_in[10];
    const float* w_alpha_b = (const float*)d_in[11];
    const float* W_h       = (const float*)d_in[12];

    const int n_node = in_sizes[2] / 64;    // 100000
    const int n_edge = in_sizes[3] / 6;     // 1000000
    const int n_rel  = in_sizes[5] / 64;    // 401
    const int n_q    = in_sizes[1];         // 256

    // Output layout (all fp32, return order).
    float* out            = (float*)d_out;
    float* out_hidden_new = out;
    float* out_alpha      = out + (size_t)n_node * 64;
    float* out_message    = out_alpha + n_edge;
    float* out_obj        = out_message + (size_t)n_edge * 64;
    float* out_alpha_temp = out_obj + n_edge;

    // Workspace layout (~35 MB).
    float* hsWs    = (float*)d_ws;                       // n_node*64
    float* Br      = hsWs + (size_t)n_node * 64;         // n_rel*64
    float* Cq      = Br + (size_t)n_rel * 64;            // n_q*64
    int*   cnt_obj = (int*)(Cq + (size_t)n_q * 64);      // n_node
    int*   offs_obj= cnt_obj + n_node;                   // n_node
    int*   cur_obj = offs_obj + n_node;                  // n_node
    int*   bsum    = cur_obj + n_node;                   // 1024
    int2*  meta    = (int2*)(bsum + 1024);               // n_edge int2 (8 MB)

    const int nb = (n_node + 1023) / 1024;               // scan blocks (98)

    (void)hipMemsetAsync(cnt_obj, 0, (size_t)n_node * sizeof(int), stream);

    // 1) hsWs = hidden @ Ws
    matmul64_kernel<<<2048, 256, 0, stream>>>(hidden, Ws, hsWs, n_node);

    // 2) B_r, C_q
    {
        int grid = (n_rel + n_q + 3) / 4;
        rel_precompute_kernel<<<grid, 256, 0, stream>>>(rela, Wr, Wqr, Wqr_b,
                                                        q_rel, Br, Cq, n_rel, n_q);
    }

    // 3) obj histogram (+ out_obj output)
    hist_kernel<<<(n_edge + 255) / 256, 256, 0, stream>>>(edges, cnt_obj,
                                                          out_obj, n_edge);

    // 4) exclusive scan: cnt_obj -> offs_obj (+ cur_obj cursor copy)
    scan_reduce_kernel<<<nb, 1024, 0, stream>>>(cnt_obj, bsum, n_node);
    scan_top_kernel<<<1, 1024, 0, stream>>>(bsum, nb);
    scan_apply_kernel<<<nb, 1024, 0, stream>>>(cnt_obj, bsum, offs_obj,
                                               cur_obj, n_node);

    // 5) counting-sort scatter (one int2 per edge)
    scatter_kernel<<<(n_edge + 255) / 256, 256, 0, stream>>>(edges, cur_obj,
                                                             meta, n_edge);

    // 6) merged per-node kernel: per-edge compute + aggregate + @W_h
    node_kernel<<<4096, 256, 0, stream>>>(meta, hsWs, hidden, rela, Br, Cq,
                                          w_alpha_w, w_alpha_b,
                                          offs_obj, cnt_obj, W_h,
                                          out_alpha, out_message,
                                          out_alpha_temp, out_hidden_new,
                                          n_node, n_edge);
}